// Round 18
// baseline (362.241 us; speedup 1.0000x reference)
//
#include <hip/hip_runtime.h>

#define NN 100000
#define NE 1600000
#define EPSV 1e-5f
#define BNODES 200
#define NBUK (NN / BNODES)  // 500
#define EPB 4096
#define NMB ((NE + EPB - 1) / EPB)  // 391
#define MATP 400

typedef unsigned short u16;
typedef __attribute__((ext_vector_type(8))) short bf16x8;
typedef __attribute__((ext_vector_type(4))) float f32x4;
typedef __attribute__((ext_vector_type(2))) float f32x2;

#define MFMA16(a, b, c) __builtin_amdgcn_mfma_f32_16x16x32_bf16(a, b, c, 0, 0, 0)

__device__ __forceinline__ u16 f2bf(float f) {
  unsigned u = __float_as_uint(f);
  unsigned r = u + 0x7fffu + ((u >> 16) & 1u);
  return (u16)(r >> 16);
}
__device__ __forceinline__ float b2f(u16 h) { return __uint_as_float(((unsigned)h) << 16); }
__device__ __forceinline__ float bflo(unsigned u) { return __uint_as_float(u << 16); }
__device__ __forceinline__ float bfhi(unsigned u) { return __uint_as_float(u & 0xffff0000u); }
__device__ __forceinline__ unsigned char f2fp8(float f) {
  return (unsigned char)(__builtin_amdgcn_cvt_pk_fp8_f32(f, 0.f, 0, false) & 0xff);
}

// ---------- multisplit CSR build (no node-level global atomics anywhere) ----------
__global__ __launch_bounds__(256) void mcount_k(const int* __restrict__ dst, int* __restrict__ mat) {
  __shared__ int cnt[NBUK];
  const int t = threadIdx.x;
  const int blk = blockIdx.x;
  for (int i = t; i < NBUK; i += 256) cnt[i] = 0;
  __syncthreads();
  const int e0 = blk * EPB;
  const int e1 = min(e0 + EPB, NE);
  for (int e = e0 + t; e < e1; e += 256) atomicAdd(&cnt[dst[e] / BNODES], 1);
  __syncthreads();
  for (int i = t; i < NBUK; i += 256) mat[i * MATP + blk] = cnt[i];
}

__global__ __launch_bounds__(256) void mscan_k(int* __restrict__ mat, int* __restrict__ btot) {
  __shared__ int sm[512];
  const int b = blockIdx.x;
  const int t = threadIdx.x;
  sm[t] = (t < NMB) ? mat[b * MATP + t] : 0;
  sm[t + 256] = (t + 256 < NMB) ? mat[b * MATP + t + 256] : 0;
  __syncthreads();
  for (int off = 1; off < 512; off <<= 1) {
    int a0 = (t >= off) ? sm[t - off] : 0;
    int a1 = (t + 256 >= off) ? sm[t + 256 - off] : 0;
    __syncthreads();
    sm[t] += a0;
    sm[t + 256] += a1;
    __syncthreads();
  }
  if (t < NMB) mat[b * MATP + t] = (t == 0) ? 0 : sm[t - 1];
  if (t + 256 < NMB) mat[b * MATP + t + 256] = sm[t + 255];
  if (t == 0) btot[b] = sm[511];
}

__global__ __launch_bounds__(512) void bscan_k(const int* __restrict__ btot, int* __restrict__ bbase) {
  __shared__ int sm[512];
  const int t = threadIdx.x;
  int v = (t < NBUK) ? btot[t] : 0;
  sm[t] = v;
  __syncthreads();
  for (int off = 1; off < 512; off <<= 1) {
    int u = (t >= off) ? sm[t - off] : 0;
    __syncthreads();
    sm[t] += u;
    __syncthreads();
  }
  if (t < NBUK) bbase[t] = sm[t] - v;
  if (t == NBUK - 1) bbase[NBUK] = sm[t];
}

__global__ __launch_bounds__(256) void mscatter_k(const int* __restrict__ src, const int* __restrict__ dst,
                                                  const int* __restrict__ mat, const int* __restrict__ bbase,
                                                  int2* __restrict__ staging) {
  __shared__ int off[NBUK];
  const int t = threadIdx.x;
  const int blk = blockIdx.x;
  for (int i = t; i < NBUK; i += 256) off[i] = bbase[i] + mat[i * MATP + blk];
  __syncthreads();
  const int e0 = blk * EPB;
  const int e1 = min(e0 + EPB, NE);
  for (int e = e0 + t; e < e1; e += 256) {
    int d = dst[e];
    int s = src[e];
    int b = d / BNODES;
    int p = atomicAdd(&off[b], 1);
    staging[p] = make_int2(s, d - b * BNODES);
  }
}

__global__ __launch_bounds__(256) void place2_k(const int* __restrict__ bbase,
                                                const int2* __restrict__ staging,
                                                int* __restrict__ ssorted, int* __restrict__ row_ptr) {
  __shared__ int cnt[BNODES];
  __shared__ int pref[256];
  const int b = blockIdx.x;
  const int t = threadIdx.x;
  const int lo = bbase[b], hi = bbase[b + 1];
  if (t < BNODES) cnt[t] = 0;
  __syncthreads();
  for (int i = lo + t; i < hi; i += 256) atomicAdd(&cnt[staging[i].y], 1);
  __syncthreads();
  int v = (t < BNODES) ? cnt[t] : 0;
  pref[t] = v;
  __syncthreads();
  for (int off = 1; off < 256; off <<= 1) {
    int u = (t >= off) ? pref[t - off] : 0;
    __syncthreads();
    pref[t] += u;
    __syncthreads();
  }
  if (t < BNODES) {
    int start = lo + pref[t] - v;
    row_ptr[b * BNODES + t] = start;
    cnt[t] = start;  // cursor
  }
  if (b == 0 && t == 0) row_ptr[NN] = NE;
  __syncthreads();
  for (int i = lo + t; i < hi; i += 256) {
    int2 e = staging[i];
    int p = atomicAdd(&cnt[e.y], 1);
    ssorted[p] = e.x;
  }
}

// ---------- fp32 -> bf16 hi/lo split + fp8 gather copy (layer-0 input) ----------
__global__ __launch_bounds__(256) void split_k(const float* __restrict__ h,
                                               u16* __restrict__ xh, u16* __restrict__ xl,
                                               unsigned char* __restrict__ x8) {
  int i = blockIdx.x * 256 + threadIdx.x;
  float4 v = reinterpret_cast<const float4*>(h)[i];
  ushort4 hv, lv;
  hv.x = f2bf(v.x); lv.x = f2bf(v.x - b2f(hv.x));
  hv.y = f2bf(v.y); lv.y = f2bf(v.y - b2f(hv.y));
  hv.z = f2bf(v.z); lv.z = f2bf(v.z - b2f(hv.z));
  hv.w = f2bf(v.w); lv.w = f2bf(v.w - b2f(hv.w));
  reinterpret_cast<ushort4*>(xh)[i] = hv;
  reinterpret_cast<ushort4*>(xl)[i] = lv;
  unsigned p8 = (unsigned)__builtin_amdgcn_cvt_pk_fp8_f32(v.x, v.y, 0, false);
  p8 = (unsigned)__builtin_amdgcn_cvt_pk_fp8_f32(v.z, v.w, (int)p8, true);
  reinterpret_cast<unsigned*>(x8)[i] = p8;
}

// ---------- weight prep: W[128][J] -> MFMA-fragment-order hi/lo ----------
__global__ __launch_bounds__(256) void wprep_k(const float* __restrict__ W, int J, int Jpad,
                                               u16* __restrict__ wh, u16* __restrict__ wl) {
  int idx = blockIdx.x * 256 + threadIdx.x;
  if (idx >= Jpad * 128) return;
  int j = idx & 7;
  int lane = (idx >> 3) & 63;
  int ks = (idx >> 9) & 3;
  int t = idx >> 11;
  int lr = lane & 15, lg = lane >> 4;
  int col = t * 16 + lr;
  int k = ks * 32 + lg * 8 + j;
  float v = (col < J) ? W[k * J + col] : 0.f;
  u16 hv = f2bf(v);
  wh[idx] = hv;
  wl[idx] = f2bf(v - b2f(hv));
}

// ---------- mean aggregation: fp8 gather table (128 B/row), fp32 accum, bf16 out ----------
__global__ __launch_bounds__(256) void agg_k(const unsigned char* __restrict__ x8,
                                             const int* __restrict__ row_ptr,
                                             const int* __restrict__ ss, u16* __restrict__ agg) {
  int gid = blockIdx.x * 256 + threadIdx.x;
  int node = gid >> 6;
  int lane = threadIdx.x & 63;
  if (node >= NN) return;
  const int half = lane >> 5;
  const int hl = lane & 31;
  int s0 = row_ptr[node], s1 = row_ptr[node + 1];
  float a0 = 0.f, a1 = 0.f, a2 = 0.f, a3 = 0.f;

  for (int base = s0; base < s1; base += 64) {
    const int nchunk = min(64, s1 - base);
    int myidx = (base + lane < s1) ? ss[base + lane] : 0;
    int i = 0;
    for (; i + 16 <= nchunk; i += 16) {
      int si[8];
#pragma unroll
      for (int u = 0; u < 8; ++u) si[u] = __shfl(myidx, i + 2 * u + half, 64);
      unsigned r[8];
#pragma unroll
      for (int u = 0; u < 8; ++u)
        r[u] = *reinterpret_cast<const unsigned*>(x8 + (size_t)si[u] * 128 + hl * 4);
#pragma unroll
      for (int u = 0; u < 8; ++u) {
        f32x2 lo = __builtin_amdgcn_cvt_pk_f32_fp8(r[u], false);
        f32x2 hi = __builtin_amdgcn_cvt_pk_f32_fp8(r[u], true);
        a0 += lo[0];
        a1 += lo[1];
        a2 += hi[0];
        a3 += hi[1];
      }
    }
    for (; i + 2 <= nchunk; i += 2) {
      int si = __shfl(myidx, i + half, 64);
      unsigned r = *reinterpret_cast<const unsigned*>(x8 + (size_t)si * 128 + hl * 4);
      f32x2 lo = __builtin_amdgcn_cvt_pk_f32_fp8(r, false);
      f32x2 hi = __builtin_amdgcn_cvt_pk_f32_fp8(r, true);
      a0 += lo[0];
      a1 += lo[1];
      a2 += hi[0];
      a3 += hi[1];
    }
    if (i < nchunk) {
      int si = __shfl(myidx, i, 64);
      if (half == 0) {
        unsigned r = *reinterpret_cast<const unsigned*>(x8 + (size_t)si * 128 + hl * 4);
        f32x2 lo = __builtin_amdgcn_cvt_pk_f32_fp8(r, false);
        f32x2 hi = __builtin_amdgcn_cvt_pk_f32_fp8(r, true);
        a0 += lo[0];
        a1 += lo[1];
        a2 += hi[0];
        a3 += hi[1];
      }
    }
  }
  a0 += __shfl_down(a0, 32, 64);
  a1 += __shfl_down(a1, 32, 64);
  a2 += __shfl_down(a2, 32, 64);
  a3 += __shfl_down(a3, 32, 64);
  if (half == 0) {
    float sc = (s1 > s0) ? 1.0f / (float)(s1 - s0) : 0.0f;
    uint2 o;
    o.x = (unsigned)f2bf(a0 * sc) | ((unsigned)f2bf(a1 * sc) << 16);
    o.y = (unsigned)f2bf(a2 * sc) | ((unsigned)f2bf(a3 * sc) << 16);
    *reinterpret_cast<uint2*>(agg + (size_t)node * 128 + hl * 4) = o;
  }
}

// ---------- column-split GEMM stream: block=64 rows; wave wv owns col-tiles 2wv..2wv+1 ----------
template <int XS>
__device__ __forceinline__ void gstream2(const u16* __restrict__ A, const u16* __restrict__ A2,
                                         const u16* __restrict__ Bh, const u16* __restrict__ Bl,
                                         int r0b, int wv, int lane, int lr, int lg,
                                         f32x4 (&acc)[2][4]) {
#pragma unroll
  for (int ks = 0; ks < 4; ++ks) {
    const int ko = ks * 32 + lg * 8;
    bf16x8 ah[4], al[4];
#pragma unroll
    for (int rg = 0; rg < 4; ++rg) {
      int row = r0b + rg * 16 + lr;
      if (row >= NN) row = NN - 1;
      ah[rg] = *reinterpret_cast<const bf16x8*>(A + (size_t)row * 128 + ko);
      if (XS) al[rg] = *reinterpret_cast<const bf16x8*>(A2 + (size_t)row * 128 + ko);
    }
#pragma unroll
    for (int t = 0; t < 2; ++t) {
      const int ct = wv * 2 + t;
      const size_t bo = (size_t)((ct * 4 + ks) * 64 + lane) * 8;
      bf16x8 bh = *reinterpret_cast<const bf16x8*>(Bh + bo);
      bf16x8 bl = *reinterpret_cast<const bf16x8*>(Bl + bo);
#pragma unroll
      for (int rg = 0; rg < 4; ++rg) {
        acc[t][rg] = MFMA16(ah[rg], bh, acc[t][rg]);
        if (XS) acc[t][rg] = MFMA16(al[rg], bh, acc[t][rg]);
        acc[t][rg] = MFMA16(ah[rg], bl, acc[t][rg]);
      }
    }
  }
}

// ---------- fused SAGE layer: col-split GEMM + bias + cross-wave LN + ReLU ----------
template <int XSPLIT>
__global__ __launch_bounds__(256, 5) void gemm_ln_k(
    const u16* __restrict__ xh, const u16* __restrict__ xl, const u16* __restrict__ ag,
    const u16* __restrict__ wsh, const u16* __restrict__ wsl,
    const u16* __restrict__ wnh, const u16* __restrict__ wnl,
    const float* __restrict__ bias, const float* __restrict__ gamma, const float* __restrict__ beta,
    u16* __restrict__ yh, unsigned char* __restrict__ y8) {
  const int lane = threadIdx.x & 63;
  const int wv = threadIdx.x >> 6;
  const int r0b = blockIdx.x * 64;
  const int lr = lane & 15, lg = lane >> 4;
  __shared__ float2 part[4][64];

  f32x4 acc[2][4];
#pragma unroll
  for (int t = 0; t < 2; ++t)
#pragma unroll
    for (int rg = 0; rg < 4; ++rg) acc[t][rg] = f32x4{0.f, 0.f, 0.f, 0.f};

  gstream2<XSPLIT>(xh, xl, wsh, wsl, r0b, wv, lane, lr, lg, acc);
  gstream2<0>(ag, nullptr, wnh, wnl, r0b, wv, lane, lr, lg, acc);

  float bcol[2], gcol[2], ecol[2];
#pragma unroll
  for (int t = 0; t < 2; ++t) {
    int c = (wv * 2 + t) * 16 + lr;
    bcol[t] = bias[c];
    gcol[t] = gamma[c];
    ecol[t] = beta[c];
  }

  // v = acc + bias (in place); partial row sums over this wave's 32 cols
#pragma unroll
  for (int rg = 0; rg < 4; ++rg)
#pragma unroll
    for (int e = 0; e < 4; ++e) {
      acc[0][rg][e] += bcol[0];
      acc[1][rg][e] += bcol[1];
      float s = acc[0][rg][e] + acc[1][rg][e];
      float q = acc[0][rg][e] * acc[0][rg][e] + acc[1][rg][e] * acc[1][rg][e];
      s += __shfl_xor(s, 1, 64);
      q += __shfl_xor(q, 1, 64);
      s += __shfl_xor(s, 2, 64);
      q += __shfl_xor(q, 2, 64);
      s += __shfl_xor(s, 4, 64);
      q += __shfl_xor(q, 4, 64);
      s += __shfl_xor(s, 8, 64);
      q += __shfl_xor(q, 8, 64);
      if (lr == 0) part[wv][rg * 16 + lg * 4 + e] = make_float2(s, q);
    }
  __syncthreads();

#pragma unroll
  for (int rg = 0; rg < 4; ++rg)
#pragma unroll
    for (int e = 0; e < 4; ++e) {
      const int rloc = rg * 16 + lg * 4 + e;
      float st = part[0][rloc].x + part[1][rloc].x + part[2][rloc].x + part[3][rloc].x;
      float qt = part[0][rloc].y + part[1][rloc].y + part[2][rloc].y + part[3][rloc].y;
      float mu = st * 0.0078125f;
      float var = qt * 0.0078125f - mu * mu;
      float inv = rsqrtf(fmaxf(var, 0.f) + EPSV);
      int row = r0b + rloc;
      if (row < NN) {
#pragma unroll
        for (int t = 0; t < 2; ++t) {
          float o = fmaxf((acc[t][rg][e] - mu) * inv * gcol[t] + ecol[t], 0.f);
          size_t idx = (size_t)row * 128 + (wv * 2 + t) * 16 + lr;
          yh[idx] = f2bf(o);
          y8[idx] = f2fp8(o);
        }
      }
    }
}

// ---------- row-blocked GEMM stream (final layer): RG*16 rows/wave ----------
template <int NT, int RG, int XS>
__device__ __forceinline__ void gstream(const u16* __restrict__ A, const u16* __restrict__ A2,
                                        const u16* __restrict__ Bh, const u16* __restrict__ Bl,
                                        int r0w, int lane, int lr, int lg, f32x4 (&acc)[NT][RG]) {
#pragma unroll
  for (int ks = 0; ks < 4; ++ks) {
    const int ko = ks * 32 + lg * 8;
    bf16x8 ah[RG], al[RG];
#pragma unroll
    for (int rg = 0; rg < RG; ++rg) {
      int row = r0w + rg * 16 + lr;
      if (row >= NN) row = NN - 1;
      ah[rg] = *reinterpret_cast<const bf16x8*>(A + (size_t)row * 128 + ko);
      if (XS) al[rg] = *reinterpret_cast<const bf16x8*>(A2 + (size_t)row * 128 + ko);
    }
#pragma unroll
    for (int t = 0; t < NT; ++t) {
      const size_t bo = (size_t)((t * 4 + ks) * 64 + lane) * 8;
      bf16x8 bh = *reinterpret_cast<const bf16x8*>(Bh + bo);
      bf16x8 bl = *reinterpret_cast<const bf16x8*>(Bl + bo);
#pragma unroll
      for (int rg = 0; rg < RG; ++rg) {
        acc[t][rg] = MFMA16(ah[rg], bh, acc[t][rg]);
        if (XS) acc[t][rg] = MFMA16(al[rg], bh, acc[t][rg]);
        acc[t][rg] = MFMA16(ah[rg], bl, acc[t][rg]);
      }
    }
  }
}

// ---------- final layer: [N,128]@[128,47] x2 + bias -> fp32 ----------
__global__ __launch_bounds__(256, 4) void gemm_out_k(
    const u16* __restrict__ x, const u16* __restrict__ ag,
    const u16* __restrict__ wsh, const u16* __restrict__ wsl,
    const u16* __restrict__ wnh, const u16* __restrict__ wnl,
    const float* __restrict__ bias, float* __restrict__ out) {
  const int lane = threadIdx.x & 63;
  const int wv = threadIdx.x >> 6;
  const int r0w = blockIdx.x * 128 + wv * 32;
  if (r0w >= NN) return;
  const int lr = lane & 15, lg = lane >> 4;

  f32x4 acc[3][2];
#pragma unroll
  for (int t = 0; t < 3; ++t)
#pragma unroll
    for (int rg = 0; rg < 2; ++rg) acc[t][rg] = f32x4{0.f, 0.f, 0.f, 0.f};

  gstream<3, 2, 0>(x, nullptr, wsh, wsl, r0w, lane, lr, lg, acc);
  gstream<3, 2, 0>(ag, nullptr, wnh, wnl, r0w, lane, lr, lg, acc);

  float bcol[3];
#pragma unroll
  for (int t = 0; t < 3; ++t) {
    int c = t * 16 + lr;
    bcol[t] = (c < 47) ? bias[c] : 0.f;
  }
#pragma unroll
  for (int rg = 0; rg < 2; ++rg)
#pragma unroll
    for (int t = 0; t < 3; ++t) {
      int col = t * 16 + lr;
      if (col < 47) {
#pragma unroll
        for (int e = 0; e < 4; ++e) {
          int row = r0w + rg * 16 + lg * 4 + e;
          if (row < NN) out[(size_t)row * 47 + col] = acc[t][rg][e] + bcol[t];
        }
      }
    }
}

extern "C" void kernel_launch(void* const* d_in, const int* in_sizes, int n_in,
                              void* d_out, int out_size, void* d_ws, size_t ws_size,
                              hipStream_t stream) {
  const float* h = (const float*)d_in[0];
  const int* src = (const int*)d_in[1];
  const int* dst = (const int*)d_in[2];
  const float* Ws0 = (const float*)d_in[3];
  const float* Wn0 = (const float*)d_in[4];
  const float* b0 = (const float*)d_in[5];
  const float* g0 = (const float*)d_in[6];
  const float* be0 = (const float*)d_in[7];
  const float* Ws1 = (const float*)d_in[8];
  const float* Wn1 = (const float*)d_in[9];
  const float* b1 = (const float*)d_in[10];
  const float* g1 = (const float*)d_in[11];
  const float* be1 = (const float*)d_in[12];
  const float* Ws2 = (const float*)d_in[13];
  const float* Wn2 = (const float*)d_in[14];
  const float* b2 = (const float*)d_in[15];
  float* out = (float*)d_out;

  // workspace layout (all 16B aligned)
  u16* x_hi = (u16*)d_ws;                       // N*128
  u16* x_lo = x_hi + (size_t)NN * 128;          // N*128 (layer-0 input lo)
  u16* aggb = x_lo + (size_t)NN * 128;          // N*128 (plain bf16 agg)
  u16* spare = aggb + (size_t)NN * 128;         // N*128 spare: [staging 12.8MB | x8 12.8MB]
  int* row_ptr = (int*)(spare + (size_t)NN * 128);   // N+1 (+pad)
  int* ssorted = row_ptr + (NN + 4);            // E
  int* btot = ssorted + NE;                     // NBUK (+pad to 512)
  int* bbase = btot + 512;                      // NBUK+1 (+pad to 512)
  u16* wbuf = (u16*)(bbase + 512);
  u16 *w0sh = wbuf, *w0sl = wbuf + 16384, *w0nh = wbuf + 32768, *w0nl = wbuf + 49152;
  u16 *w1sh = wbuf + 65536, *w1sl = wbuf + 81920, *w1nh = wbuf + 98304, *w1nl = wbuf + 114688;
  u16 *w2sh = wbuf + 131072, *w2sl = wbuf + 137216, *w2nh = wbuf + 143360, *w2nl = wbuf + 149504;
  // CSR temps (dead after place2_k) + fp8 gather table (disjoint halves of spare):
  int* mat = (int*)aggb;                          // NBUK*MATP local offsets (800 KB)
  int2* staging = (int2*)spare;                   // E packed (src, dst_local) (12.8 MB, first half)
  unsigned char* x8 = (unsigned char*)(spare + (size_t)NN * 64);  // N*128 fp8 (12.8 MB, second half)

  // CSR build: atomic-free multisplit -> bucket scatter (+row_ptr from bucket hist)
  mcount_k<<<NMB, 256, 0, stream>>>(dst, mat);
  mscan_k<<<NBUK, 256, 0, stream>>>(mat, btot);
  bscan_k<<<1, 512, 0, stream>>>(btot, bbase);
  mscatter_k<<<NMB, 256, 0, stream>>>(src, dst, mat, bbase, staging);
  place2_k<<<NBUK, 256, 0, stream>>>(bbase, staging, ssorted, row_ptr);

  // feature split (bf16 hi/lo + fp8 gather copy) + weight prep (fragment-order)
  split_k<<<(NN * 128 / 4 + 255) / 256, 256, 0, stream>>>(h, x_hi, x_lo, x8);
  wprep_k<<<64, 256, 0, stream>>>(Ws0, 128, 128, w0sh, w0sl);
  wprep_k<<<64, 256, 0, stream>>>(Wn0, 128, 128, w0nh, w0nl);
  wprep_k<<<64, 256, 0, stream>>>(Ws1, 128, 128, w1sh, w1sl);
  wprep_k<<<64, 256, 0, stream>>>(Wn1, 128, 128, w1nh, w1nl);
  wprep_k<<<24, 256, 0, stream>>>(Ws2, 47, 48, w2sh, w2sl);
  wprep_k<<<24, 256, 0, stream>>>(Wn2, 47, 48, w2nh, w2nl);

  const int AGG_GRID = (NN * 64 + 255) / 256;
  const int GEMM_LN_GRID = (NN + 63) / 64;     // 1563 blocks (~6.1/CU)
  const int GEMM_OUT_GRID = (NN + 127) / 128;  // 782

  // layer 0 (x split hi+lo)
  agg_k<<<AGG_GRID, 256, 0, stream>>>(x8, row_ptr, ssorted, aggb);
  gemm_ln_k<1><<<GEMM_LN_GRID, 256, 0, stream>>>(x_hi, x_lo, aggb,
                                                 w0sh, w0sl, w0nh, w0nl, b0, g0, be0, x_hi, x8);
  // layer 1 (plain bf16 activations, in-place)
  agg_k<<<AGG_GRID, 256, 0, stream>>>(x8, row_ptr, ssorted, aggb);
  gemm_ln_k<0><<<GEMM_LN_GRID, 256, 0, stream>>>(x_hi, nullptr, aggb,
                                                 w1sh, w1sl, w1nh, w1nl, b1, g1, be1, x_hi, x8);
  // layer 2
  agg_k<<<AGG_GRID, 256, 0, stream>>>(x8, row_ptr, ssorted, aggb);
  gemm_out_k<<<GEMM_OUT_GRID, 256, 0, stream>>>(x_hi, aggb,
                                                w2sh, w2sl, w2nh, w2nl, b2, out);
}

// Round 19
// 345.943 us; speedup vs baseline: 1.0471x; 1.0471x over previous
//
#include <hip/hip_runtime.h>

#define NN 100000
#define NE 1600000
#define EPSV 1e-5f
#define BNODES 200
#define NBUK (NN / BNODES)  // 500
#define EPB 4096
#define NMB ((NE + EPB - 1) / EPB)  // 391
#define MATP 400

typedef unsigned short u16;
typedef __attribute__((ext_vector_type(8))) short bf16x8;
typedef __attribute__((ext_vector_type(4))) float f32x4;
typedef __attribute__((ext_vector_type(2))) float f32x2;

#define MFMA16(a, b, c) __builtin_amdgcn_mfma_f32_16x16x32_bf16(a, b, c, 0, 0, 0)

__device__ __forceinline__ u16 f2bf(float f) {
  unsigned u = __float_as_uint(f);
  unsigned r = u + 0x7fffu + ((u >> 16) & 1u);
  return (u16)(r >> 16);
}
__device__ __forceinline__ float b2f(u16 h) { return __uint_as_float(((unsigned)h) << 16); }
__device__ __forceinline__ float bflo(unsigned u) { return __uint_as_float(u << 16); }
__device__ __forceinline__ float bfhi(unsigned u) { return __uint_as_float(u & 0xffff0000u); }
__device__ __forceinline__ unsigned char f2fp8(float f) {
  return (unsigned char)(__builtin_amdgcn_cvt_pk_fp8_f32(f, 0.f, 0, false) & 0xff);
}

// ---------- multisplit CSR build (no node-level global atomics anywhere) ----------
__global__ __launch_bounds__(256) void mcount_k(const int* __restrict__ dst, int* __restrict__ mat) {
  __shared__ int cnt[NBUK];
  const int t = threadIdx.x;
  const int blk = blockIdx.x;
  for (int i = t; i < NBUK; i += 256) cnt[i] = 0;
  __syncthreads();
  const int e0 = blk * EPB;
  const int e1 = min(e0 + EPB, NE);
  for (int e = e0 + t; e < e1; e += 256) atomicAdd(&cnt[dst[e] / BNODES], 1);
  __syncthreads();
  for (int i = t; i < NBUK; i += 256) mat[i * MATP + blk] = cnt[i];
}

__global__ __launch_bounds__(256) void mscan_k(int* __restrict__ mat, int* __restrict__ btot) {
  __shared__ int sm[512];
  const int b = blockIdx.x;
  const int t = threadIdx.x;
  sm[t] = (t < NMB) ? mat[b * MATP + t] : 0;
  sm[t + 256] = (t + 256 < NMB) ? mat[b * MATP + t + 256] : 0;
  __syncthreads();
  for (int off = 1; off < 512; off <<= 1) {
    int a0 = (t >= off) ? sm[t - off] : 0;
    int a1 = (t + 256 >= off) ? sm[t + 256 - off] : 0;
    __syncthreads();
    sm[t] += a0;
    sm[t + 256] += a1;
    __syncthreads();
  }
  if (t < NMB) mat[b * MATP + t] = (t == 0) ? 0 : sm[t - 1];
  if (t + 256 < NMB) mat[b * MATP + t + 256] = sm[t + 255];
  if (t == 0) btot[b] = sm[511];
}

__global__ __launch_bounds__(512) void bscan_k(const int* __restrict__ btot, int* __restrict__ bbase) {
  __shared__ int sm[512];
  const int t = threadIdx.x;
  int v = (t < NBUK) ? btot[t] : 0;
  sm[t] = v;
  __syncthreads();
  for (int off = 1; off < 512; off <<= 1) {
    int u = (t >= off) ? sm[t - off] : 0;
    __syncthreads();
    sm[t] += u;
    __syncthreads();
  }
  if (t < NBUK) bbase[t] = sm[t] - v;
  if (t == NBUK - 1) bbase[NBUK] = sm[t];
}

__global__ __launch_bounds__(256) void mscatter_k(const int* __restrict__ src, const int* __restrict__ dst,
                                                  const int* __restrict__ mat, const int* __restrict__ bbase,
                                                  int2* __restrict__ staging) {
  __shared__ int off[NBUK];
  const int t = threadIdx.x;
  const int blk = blockIdx.x;
  for (int i = t; i < NBUK; i += 256) off[i] = bbase[i] + mat[i * MATP + blk];
  __syncthreads();
  const int e0 = blk * EPB;
  const int e1 = min(e0 + EPB, NE);
  for (int e = e0 + t; e < e1; e += 256) {
    int d = dst[e];
    int s = src[e];
    int b = d / BNODES;
    int p = atomicAdd(&off[b], 1);
    staging[p] = make_int2(s, d - b * BNODES);
  }
}

__global__ __launch_bounds__(256) void place2_k(const int* __restrict__ bbase,
                                                const int2* __restrict__ staging,
                                                int* __restrict__ ssorted, int* __restrict__ row_ptr) {
  __shared__ int cnt[BNODES];
  __shared__ int pref[256];
  const int b = blockIdx.x;
  const int t = threadIdx.x;
  const int lo = bbase[b], hi = bbase[b + 1];
  if (t < BNODES) cnt[t] = 0;
  __syncthreads();
  for (int i = lo + t; i < hi; i += 256) atomicAdd(&cnt[staging[i].y], 1);
  __syncthreads();
  int v = (t < BNODES) ? cnt[t] : 0;
  pref[t] = v;
  __syncthreads();
  for (int off = 1; off < 256; off <<= 1) {
    int u = (t >= off) ? pref[t - off] : 0;
    __syncthreads();
    pref[t] += u;
    __syncthreads();
  }
  if (t < BNODES) {
    int start = lo + pref[t] - v;
    row_ptr[b * BNODES + t] = start;
    cnt[t] = start;  // cursor
  }
  if (b == 0 && t == 0) row_ptr[NN] = NE;
  __syncthreads();
  for (int i = lo + t; i < hi; i += 256) {
    int2 e = staging[i];
    int p = atomicAdd(&cnt[e.y], 1);
    ssorted[p] = e.x;
  }
}

// ---------- fp32 -> bf16 hi/lo split + fp8 gather copy (layer-0 input) ----------
__global__ __launch_bounds__(256) void split_k(const float* __restrict__ h,
                                               u16* __restrict__ xh, u16* __restrict__ xl,
                                               unsigned char* __restrict__ x8) {
  int i = blockIdx.x * 256 + threadIdx.x;
  float4 v = reinterpret_cast<const float4*>(h)[i];
  ushort4 hv, lv;
  hv.x = f2bf(v.x); lv.x = f2bf(v.x - b2f(hv.x));
  hv.y = f2bf(v.y); lv.y = f2bf(v.y - b2f(hv.y));
  hv.z = f2bf(v.z); lv.z = f2bf(v.z - b2f(hv.z));
  hv.w = f2bf(v.w); lv.w = f2bf(v.w - b2f(hv.w));
  reinterpret_cast<ushort4*>(xh)[i] = hv;
  reinterpret_cast<ushort4*>(xl)[i] = lv;
  unsigned p8 = (unsigned)__builtin_amdgcn_cvt_pk_fp8_f32(v.x, v.y, 0, false);
  p8 = (unsigned)__builtin_amdgcn_cvt_pk_fp8_f32(v.z, v.w, (int)p8, true);
  reinterpret_cast<unsigned*>(x8)[i] = p8;
}

// ---------- weight prep: W[128][J] -> MFMA-fragment-order hi/lo ----------
__global__ __launch_bounds__(256) void wprep_k(const float* __restrict__ W, int J, int Jpad,
                                               u16* __restrict__ wh, u16* __restrict__ wl) {
  int idx = blockIdx.x * 256 + threadIdx.x;
  if (idx >= Jpad * 128) return;
  int j = idx & 7;
  int lane = (idx >> 3) & 63;
  int ks = (idx >> 9) & 3;
  int t = idx >> 11;
  int lr = lane & 15, lg = lane >> 4;
  int col = t * 16 + lr;
  int k = ks * 32 + lg * 8 + j;
  float v = (col < J) ? W[k * J + col] : 0.f;
  u16 hv = f2bf(v);
  wh[idx] = hv;
  wl[idx] = f2bf(v - b2f(hv));
}

// ---------- mean aggregation: fp8 gather table (128 B/row), fp32 accum, bf16 out ----------
__global__ __launch_bounds__(256) void agg_k(const unsigned char* __restrict__ x8,
                                             const int* __restrict__ row_ptr,
                                             const int* __restrict__ ss, u16* __restrict__ agg) {
  int gid = blockIdx.x * 256 + threadIdx.x;
  int node = gid >> 6;
  int lane = threadIdx.x & 63;
  if (node >= NN) return;
  const int half = lane >> 5;
  const int hl = lane & 31;
  int s0 = row_ptr[node], s1 = row_ptr[node + 1];
  float a0 = 0.f, a1 = 0.f, a2 = 0.f, a3 = 0.f;

  for (int base = s0; base < s1; base += 64) {
    const int nchunk = min(64, s1 - base);
    int myidx = (base + lane < s1) ? ss[base + lane] : 0;
    int i = 0;
    for (; i + 16 <= nchunk; i += 16) {
      int si[8];
#pragma unroll
      for (int u = 0; u < 8; ++u) si[u] = __shfl(myidx, i + 2 * u + half, 64);
      unsigned r[8];
#pragma unroll
      for (int u = 0; u < 8; ++u)
        r[u] = *reinterpret_cast<const unsigned*>(x8 + (size_t)si[u] * 128 + hl * 4);
#pragma unroll
      for (int u = 0; u < 8; ++u) {
        f32x2 lo = __builtin_amdgcn_cvt_pk_f32_fp8(r[u], false);
        f32x2 hi = __builtin_amdgcn_cvt_pk_f32_fp8(r[u], true);
        a0 += lo[0];
        a1 += lo[1];
        a2 += hi[0];
        a3 += hi[1];
      }
    }
    for (; i + 2 <= nchunk; i += 2) {
      int si = __shfl(myidx, i + half, 64);
      unsigned r = *reinterpret_cast<const unsigned*>(x8 + (size_t)si * 128 + hl * 4);
      f32x2 lo = __builtin_amdgcn_cvt_pk_f32_fp8(r, false);
      f32x2 hi = __builtin_amdgcn_cvt_pk_f32_fp8(r, true);
      a0 += lo[0];
      a1 += lo[1];
      a2 += hi[0];
      a3 += hi[1];
    }
    if (i < nchunk) {
      int si = __shfl(myidx, i, 64);
      if (half == 0) {
        unsigned r = *reinterpret_cast<const unsigned*>(x8 + (size_t)si * 128 + hl * 4);
        f32x2 lo = __builtin_amdgcn_cvt_pk_f32_fp8(r, false);
        f32x2 hi = __builtin_amdgcn_cvt_pk_f32_fp8(r, true);
        a0 += lo[0];
        a1 += lo[1];
        a2 += hi[0];
        a3 += hi[1];
      }
    }
  }
  a0 += __shfl_down(a0, 32, 64);
  a1 += __shfl_down(a1, 32, 64);
  a2 += __shfl_down(a2, 32, 64);
  a3 += __shfl_down(a3, 32, 64);
  if (half == 0) {
    float sc = (s1 > s0) ? 1.0f / (float)(s1 - s0) : 0.0f;
    uint2 o;
    o.x = (unsigned)f2bf(a0 * sc) | ((unsigned)f2bf(a1 * sc) << 16);
    o.y = (unsigned)f2bf(a2 * sc) | ((unsigned)f2bf(a3 * sc) << 16);
    *reinterpret_cast<uint2*>(agg + (size_t)node * 128 + hl * 4) = o;
  }
}

// ---------- register-blocked GEMM stream: RG*16 rows/wave, fragment-order B ----------
template <int NT, int RG, int XS>
__device__ __forceinline__ void gstream(const u16* __restrict__ A, const u16* __restrict__ A2,
                                        const u16* __restrict__ Bh, const u16* __restrict__ Bl,
                                        int r0w, int lane, int lr, int lg, f32x4 (&acc)[NT][RG]) {
#pragma unroll
  for (int ks = 0; ks < 4; ++ks) {
    const int ko = ks * 32 + lg * 8;
    bf16x8 ah[RG], al[RG];
#pragma unroll
    for (int rg = 0; rg < RG; ++rg) {
      int row = r0w + rg * 16 + lr;
      if (row >= NN) row = NN - 1;
      ah[rg] = *reinterpret_cast<const bf16x8*>(A + (size_t)row * 128 + ko);
      if (XS) al[rg] = *reinterpret_cast<const bf16x8*>(A2 + (size_t)row * 128 + ko);
    }
#pragma unroll
    for (int t = 0; t < NT; ++t) {
      const size_t bo = (size_t)((t * 4 + ks) * 64 + lane) * 8;
      bf16x8 bh = *reinterpret_cast<const bf16x8*>(Bh + bo);
      bf16x8 bl = *reinterpret_cast<const bf16x8*>(Bl + bo);
#pragma unroll
      for (int rg = 0; rg < RG; ++rg) {
        acc[t][rg] = MFMA16(ah[rg], bh, acc[t][rg]);
        if (XS) acc[t][rg] = MFMA16(al[rg], bh, acc[t][rg]);
        acc[t][rg] = MFMA16(ah[rg], bl, acc[t][rg]);
      }
    }
  }
}

#define RGN 2  // 32 rows/wave, 128 rows/block (measured optimum across RGN=4/2/1 and col-split)

// ---------- fused SAGE layer: GEMM + bias + LN + ReLU; writes bf16 + fp8 copies ----------
template <int XSPLIT>
__global__ __launch_bounds__(256, 4) void gemm_ln_k(
    const u16* __restrict__ xh, const u16* __restrict__ xl, const u16* __restrict__ ag,
    const u16* __restrict__ wsh, const u16* __restrict__ wsl,
    const u16* __restrict__ wnh, const u16* __restrict__ wnl,
    const float* __restrict__ bias, const float* __restrict__ gamma, const float* __restrict__ beta,
    u16* __restrict__ yh, unsigned char* __restrict__ y8) {
  const int lane = threadIdx.x & 63;
  const int wv = threadIdx.x >> 6;
  const int r0w = blockIdx.x * (RGN * 64) + wv * (RGN * 16);
  if (r0w >= NN) return;
  const int lr = lane & 15, lg = lane >> 4;

  f32x4 acc[8][RGN];
#pragma unroll
  for (int t = 0; t < 8; ++t)
#pragma unroll
    for (int rg = 0; rg < RGN; ++rg) acc[t][rg] = f32x4{0.f, 0.f, 0.f, 0.f};

  gstream<8, RGN, XSPLIT>(xh, xl, wsh, wsl, r0w, lane, lr, lg, acc);
  gstream<8, RGN, 0>(ag, nullptr, wnh, wnl, r0w, lane, lr, lg, acc);

  float bcol[8], gcol[8], ecol[8];
#pragma unroll
  for (int t = 0; t < 8; ++t) {
    int c = t * 16 + lr;
    bcol[t] = bias[c];
    gcol[t] = gamma[c];
    ecol[t] = beta[c];
  }

#pragma unroll
  for (int rg = 0; rg < RGN; ++rg) {
    float v[8][4];
#pragma unroll
    for (int t = 0; t < 8; ++t)
#pragma unroll
      for (int e = 0; e < 4; ++e) v[t][e] = acc[t][rg][e] + bcol[t];
    float mu[4], inv[4];
#pragma unroll
    for (int e = 0; e < 4; ++e) {
      float s = 0.f;
#pragma unroll
      for (int t = 0; t < 8; ++t) s += v[t][e];
      s += __shfl_xor(s, 1, 64);
      s += __shfl_xor(s, 2, 64);
      s += __shfl_xor(s, 4, 64);
      s += __shfl_xor(s, 8, 64);
      mu[e] = s * 0.0078125f;
    }
#pragma unroll
    for (int e = 0; e < 4; ++e) {
      float q = 0.f;
#pragma unroll
      for (int t = 0; t < 8; ++t) {
        float d = v[t][e] - mu[e];
        q += d * d;
      }
      q += __shfl_xor(q, 1, 64);
      q += __shfl_xor(q, 2, 64);
      q += __shfl_xor(q, 4, 64);
      q += __shfl_xor(q, 8, 64);
      inv[e] = rsqrtf(q * 0.0078125f + EPSV);
    }
#pragma unroll
    for (int t = 0; t < 8; ++t)
#pragma unroll
      for (int e = 0; e < 4; ++e) {
        int row = r0w + rg * 16 + lg * 4 + e;
        if (row < NN) {
          float o = fmaxf((v[t][e] - mu[e]) * inv[e] * gcol[t] + ecol[t], 0.f);
          size_t idx = (size_t)row * 128 + t * 16 + lr;
          yh[idx] = f2bf(o);
          y8[idx] = f2fp8(o);
        }
      }
  }
}

// ---------- final layer: [N,128]@[128,47] x2 + bias -> fp32 ----------
__global__ __launch_bounds__(256, 4) void gemm_out_k(
    const u16* __restrict__ x, const u16* __restrict__ ag,
    const u16* __restrict__ wsh, const u16* __restrict__ wsl,
    const u16* __restrict__ wnh, const u16* __restrict__ wnl,
    const float* __restrict__ bias, float* __restrict__ out) {
  const int lane = threadIdx.x & 63;
  const int wv = threadIdx.x >> 6;
  const int r0w = blockIdx.x * (RGN * 64) + wv * (RGN * 16);
  if (r0w >= NN) return;
  const int lr = lane & 15, lg = lane >> 4;

  f32x4 acc[3][RGN];
#pragma unroll
  for (int t = 0; t < 3; ++t)
#pragma unroll
    for (int rg = 0; rg < RGN; ++rg) acc[t][rg] = f32x4{0.f, 0.f, 0.f, 0.f};

  gstream<3, RGN, 0>(x, nullptr, wsh, wsl, r0w, lane, lr, lg, acc);
  gstream<3, RGN, 0>(ag, nullptr, wnh, wnl, r0w, lane, lr, lg, acc);

  float bcol[3];
#pragma unroll
  for (int t = 0; t < 3; ++t) {
    int c = t * 16 + lr;
    bcol[t] = (c < 47) ? bias[c] : 0.f;
  }
#pragma unroll
  for (int rg = 0; rg < RGN; ++rg)
#pragma unroll
    for (int t = 0; t < 3; ++t) {
      int col = t * 16 + lr;
      if (col < 47) {
#pragma unroll
        for (int e = 0; e < 4; ++e) {
          int row = r0w + rg * 16 + lg * 4 + e;
          if (row < NN) out[(size_t)row * 47 + col] = acc[t][rg][e] + bcol[t];
        }
      }
    }
}

extern "C" void kernel_launch(void* const* d_in, const int* in_sizes, int n_in,
                              void* d_out, int out_size, void* d_ws, size_t ws_size,
                              hipStream_t stream) {
  const float* h = (const float*)d_in[0];
  const int* src = (const int*)d_in[1];
  const int* dst = (const int*)d_in[2];
  const float* Ws0 = (const float*)d_in[3];
  const float* Wn0 = (const float*)d_in[4];
  const float* b0 = (const float*)d_in[5];
  const float* g0 = (const float*)d_in[6];
  const float* be0 = (const float*)d_in[7];
  const float* Ws1 = (const float*)d_in[8];
  const float* Wn1 = (const float*)d_in[9];
  const float* b1 = (const float*)d_in[10];
  const float* g1 = (const float*)d_in[11];
  const float* be1 = (const float*)d_in[12];
  const float* Ws2 = (const float*)d_in[13];
  const float* Wn2 = (const float*)d_in[14];
  const float* b2 = (const float*)d_in[15];
  float* out = (float*)d_out;

  // workspace layout (all 16B aligned)
  u16* x_hi = (u16*)d_ws;                       // N*128
  u16* x_lo = x_hi + (size_t)NN * 128;          // N*128 (layer-0 input lo)
  u16* aggb = x_lo + (size_t)NN * 128;          // N*128 (plain bf16 agg)
  u16* spare = aggb + (size_t)NN * 128;         // N*128 spare: [staging 12.8MB | x8 12.8MB]
  int* row_ptr = (int*)(spare + (size_t)NN * 128);   // N+1 (+pad)
  int* ssorted = row_ptr + (NN + 4);            // E
  int* btot = ssorted + NE;                     // NBUK (+pad to 512)
  int* bbase = btot + 512;                      // NBUK+1 (+pad to 512)
  u16* wbuf = (u16*)(bbase + 512);
  u16 *w0sh = wbuf, *w0sl = wbuf + 16384, *w0nh = wbuf + 32768, *w0nl = wbuf + 49152;
  u16 *w1sh = wbuf + 65536, *w1sl = wbuf + 81920, *w1nh = wbuf + 98304, *w1nl = wbuf + 114688;
  u16 *w2sh = wbuf + 131072, *w2sl = wbuf + 137216, *w2nh = wbuf + 143360, *w2nl = wbuf + 149504;
  // CSR temps (dead after place2_k) + fp8 gather table (disjoint halves of spare):
  int* mat = (int*)aggb;                          // NBUK*MATP local offsets (800 KB)
  int2* staging = (int2*)spare;                   // E packed (src, dst_local) (12.8 MB, first half)
  unsigned char* x8 = (unsigned char*)(spare + (size_t)NN * 64);  // N*128 fp8 (12.8 MB, second half)

  // CSR build: atomic-free multisplit -> bucket scatter (+row_ptr from bucket hist)
  mcount_k<<<NMB, 256, 0, stream>>>(dst, mat);
  mscan_k<<<NBUK, 256, 0, stream>>>(mat, btot);
  bscan_k<<<1, 512, 0, stream>>>(btot, bbase);
  mscatter_k<<<NMB, 256, 0, stream>>>(src, dst, mat, bbase, staging);
  place2_k<<<NBUK, 256, 0, stream>>>(bbase, staging, ssorted, row_ptr);

  // feature split (bf16 hi/lo + fp8 gather copy) + weight prep (fragment-order)
  split_k<<<(NN * 128 / 4 + 255) / 256, 256, 0, stream>>>(h, x_hi, x_lo, x8);
  wprep_k<<<64, 256, 0, stream>>>(Ws0, 128, 128, w0sh, w0sl);
  wprep_k<<<64, 256, 0, stream>>>(Wn0, 128, 128, w0nh, w0nl);
  wprep_k<<<64, 256, 0, stream>>>(Ws1, 128, 128, w1sh, w1sl);
  wprep_k<<<64, 256, 0, stream>>>(Wn1, 128, 128, w1nh, w1nl);
  wprep_k<<<24, 256, 0, stream>>>(Ws2, 47, 48, w2sh, w2sl);
  wprep_k<<<24, 256, 0, stream>>>(Wn2, 47, 48, w2nh, w2nl);

  const int AGG_GRID = (NN * 64 + 255) / 256;
  const int GEMM_GRID = (NN + RGN * 64 - 1) / (RGN * 64);

  // layer 0 (x split hi+lo)
  agg_k<<<AGG_GRID, 256, 0, stream>>>(x8, row_ptr, ssorted, aggb);
  gemm_ln_k<1><<<GEMM_GRID, 256, 0, stream>>>(x_hi, x_lo, aggb,
                                              w0sh, w0sl, w0nh, w0nl, b0, g0, be0, x_hi, x8);
  // layer 1 (plain bf16 activations, in-place)
  agg_k<<<AGG_GRID, 256, 0, stream>>>(x8, row_ptr, ssorted, aggb);
  gemm_ln_k<0><<<GEMM_GRID, 256, 0, stream>>>(x_hi, nullptr, aggb,
                                              w1sh, w1sl, w1nh, w1nl, b1, g1, be1, x_hi, x8);
  // layer 2
  agg_k<<<AGG_GRID, 256, 0, stream>>>(x8, row_ptr, ssorted, aggb);
  gemm_out_k<<<GEMM_GRID, 256, 0, stream>>>(x_hi, aggb,
                                            w2sh, w2sl, w2nh, w2nl, b2, out);
}